// Round 4
// baseline (161.919 us; speedup 1.0000x reference)
//
#include <hip/hip_runtime.h>
#include <hip/hip_bf16.h>

typedef unsigned short u16;
typedef __attribute__((ext_vector_type(8))) short short8;
typedef __attribute__((ext_vector_type(4))) float float4v;

#define N_ROWS 16384   // B*H*W = 16*32*32
#define M_COLS 8192
#define KDIM   128
#define SHIFT  64.0f   // fixed lse shift: A<=0, alpha~-0.5 -> exp(A+64) in range
#define STRIPES 128    // 16384 / 128 rows per block
#define SPLITS  8      // col splits; each block covers 1024 cols
#define TILES   16     // 1024 / 64 cols per tile

// RNE fp32 -> bf16 (data has no NaN)
__device__ inline u16 f2bf(float f) {
  unsigned u = __builtin_bit_cast(unsigned, f);
  unsigned r = (u + 0x7fffu + ((u >> 16) & 1u)) >> 16;
  return (u16)r;
}

// ---------------------------------------------------------------------------
// prep (fused): blocks 0..511 = prep_z (one per (b,h)); blocks 512..639 =
// prep_e. Block 512 also zero-inits the fin ticket/accumulators (ws is
// re-poisoned before every replay).
// ---------------------------------------------------------------------------
__global__ void prep(const float* __restrict__ z, const float* __restrict__ e,
                     u16* __restrict__ zf, u16* __restrict__ ef,
                     float* __restrict__ zsq, float* __restrict__ esq,
                     double* __restrict__ dacc, unsigned* __restrict__ dcnt) {
  if (blockIdx.x < 512) {
    const int b = blockIdx.x >> 5, h = blockIdx.x & 31;
    __shared__ float tile[128 * 33];
    __shared__ float psum[8][32];
    const float* src = z + ((size_t)b * 128 * 32 + h) * 32;  // + c*1024 + w
    for (int idx = threadIdx.x; idx < 4096; idx += 256) {
      int c = idx >> 5, w = idx & 31;
      tile[c * 33 + w] = src[c * 1024 + w];
    }
    __syncthreads();
    {
      int w = threadIdx.x & 31, cg = threadIdx.x >> 5;
      float s = 0.f;
#pragma unroll
      for (int cc = 0; cc < 16; ++cc) {
        float v = tile[(cg * 16 + cc) * 33 + w];
        s = fmaf(v, v, s);
      }
      psum[cg][w] = s;
    }
    for (int idx = threadIdx.x; idx < 512; idx += 256) {
      int w = idx >> 4, g = idx & 15;
      short8 v;
#pragma unroll
      for (int cc = 0; cc < 8; ++cc) v[cc] = (short)f2bf(tile[(g * 8 + cc) * 33 + w]);
      *(short8*)&zf[((size_t)b * 1024 + h * 32 + w) * 128 + g * 8] = v;
    }
    __syncthreads();
    if (threadIdx.x < 32) {
      int w = threadIdx.x;
      float s = 0.f;
#pragma unroll
      for (int cg = 0; cg < 8; ++cg) s += psum[cg][w];
      zsq[b * 1024 + h * 32 + w] = s;
    }
  } else {
    if (blockIdx.x == 512 && threadIdx.x == 0) {
      __hip_atomic_store(&dacc[0], 0.0, __ATOMIC_RELAXED, __HIP_MEMORY_SCOPE_AGENT);
      __hip_atomic_store(&dacc[1], 0.0, __ATOMIC_RELAXED, __HIP_MEMORY_SCOPE_AGENT);
      __hip_atomic_store(dcnt, 0u, __ATOMIC_RELAXED, __HIP_MEMORY_SCOPE_AGENT);
    }
    const int gw = ((blockIdx.x - 512) * 256 + threadIdx.x) >> 6;  // 512 waves
    const int ln = threadIdx.x & 63;
    for (int r = gw; r < M_COLS; r += 512) {
      float2 v = *(const float2*)&e[r * 128 + ln * 2];
      unsigned pk = (unsigned)f2bf(v.x) | ((unsigned)f2bf(v.y) << 16);
      *(unsigned*)&ef[r * 128 + ln * 2] = pk;
      float s = fmaf(v.x, v.x, v.y * v.y);
#pragma unroll
      for (int sh = 1; sh < 64; sh <<= 1) s += __shfl_xor(s, sh);
      if (ln == 0) esq[r] = s;
    }
  }
}

// ---------------------------------------------------------------------------
// gemm_lse: persistent-A. Block = 4 waves = 128-row stripe; wave = 32 rows,
// all K=128 A-frags in regs (8 x short8 = 32 VGPRs). Loop over 16 B-tiles
// (64 cols) of this block's 1024-col split, double-buffered LDS staging via
// global_load_lds (XOR swizzle). Per iter: [barrier; mma(t); stage(t+1);
// epilogue(t)] so staging overlaps the VALU-heavy epilogue. rowsum in regs
// (flushed once); colsum via LDS atomics -> non-atomic per-block partials.
// 1024 blocks -> 4 blocks/CU (launch_bounds(256,4)), 16 waves/CU.
// ---------------------------------------------------------------------------
__global__ __launch_bounds__(256, 4) void gemm_lse(
    const u16* __restrict__ zf, const u16* __restrict__ ef,
    const float* __restrict__ zsq, const float* __restrict__ esq,
    const float* __restrict__ log_sigma,
    float* __restrict__ rpart, float* __restrict__ cpart) {
  __shared__ __align__(16) u16 et[2][64 * 128];  // 2 x 16 KB
  __shared__ float colacc[1024];
  const int tid = threadIdx.x;
  const int ln = tid & 63, wv = tid >> 6;
  const int l15 = ln & 15, q = ln >> 4;
  const int stripe = blockIdx.x, split = blockIdx.y;
  const int colbase = split * 1024;

  for (int i = tid; i < 1024; i += 256) colacc[i] = 0.f;

  // persistent A fragments: 32 rows x K=128 per wave
  short8 af[2][4];
#pragma unroll
  for (int i = 0; i < 2; ++i)
#pragma unroll
    for (int kk = 0; kk < 4; ++kk)
      af[i][kk] = *(const short8*)(zf +
          (size_t)(stripe * 128 + wv * 32 + i * 16 + l15) * 128 + kk * 32 + q * 8);

  const float lsv = log_sigma[0];
  const float sg = __expf(lsv);
  const float alpha = -0.5f / (sg * sg);
  const float L2E = 1.44269504088896f;
  const float ca = alpha * L2E, cb = SHIFT * L2E, m2ca = -2.0f * ca;

  float4v zbl[2];
#pragma unroll
  for (int i = 0; i < 2; ++i) {
    float4v zs = *(const float4v*)(zsq + stripe * 128 + wv * 32 + i * 16 + q * 4);
#pragma unroll
    for (int r = 0; r < 4; ++r) zbl[i][r] = fmaf(ca, zs[r], cb);
  }

  float2 rs2[2][2];
#pragma unroll
  for (int i = 0; i < 2; ++i)
#pragma unroll
    for (int p = 0; p < 2; ++p) rs2[i][p] = make_float2(0.f, 0.f);

#define STAGE(tt)                                                              \
  do {                                                                         \
    const u16* efb = ef + (size_t)(colbase + (tt) * 64) * 128;                 \
    u16* dstb = et[(tt) & 1];                                                  \
    _Pragma("unroll")                                                          \
    for (int it = 0; it < 4; ++it) {                                           \
      int u = it * 256 + tid;                                                  \
      int r = u >> 4, p_ = u & 15;                                             \
      int g = p_ ^ (r & 15);                                                   \
      __builtin_amdgcn_global_load_lds(                                        \
          (const __attribute__((address_space(1))) unsigned int*)(efb + r * 128 + g * 8), \
          (__attribute__((address_space(3))) unsigned int*)(dstb + (it * 256 + wv * 64) * 8), \
          16, 0, 0);                                                           \
    }                                                                          \
  } while (0)

  STAGE(0);

  for (int t = 0; t < TILES; ++t) {
    // hoist esq loads so the epilogue doesn't stall on them
    float ebv[4];
#pragma unroll
    for (int j = 0; j < 4; ++j) ebv[j] = ca * esq[colbase + t * 64 + j * 16 + l15];

    __syncthreads();
    const u16* bb = et[t & 1];

    float4v acc[2][4];
#pragma unroll
    for (int kk = 0; kk < 4; ++kk) {
      short8 bfr[4];
      const int poff = ((kk * 4 + q) ^ l15) * 8;
#pragma unroll
      for (int j = 0; j < 4; ++j)
        bfr[j] = *(const short8*)(bb + (j * 16 + l15) * 128 + poff);
      if (kk == 0) {
#pragma unroll
        for (int i = 0; i < 2; ++i)
#pragma unroll
          for (int j = 0; j < 4; ++j)
            acc[i][j] = __builtin_amdgcn_mfma_f32_16x16x32_bf16(
                af[i][0], bfr[j], (float4v){0.f, 0.f, 0.f, 0.f}, 0, 0, 0);
      } else {
#pragma unroll
        for (int i = 0; i < 2; ++i)
#pragma unroll
          for (int j = 0; j < 4; ++j)
            acc[i][j] = __builtin_amdgcn_mfma_f32_16x16x32_bf16(
                af[i][kk], bfr[j], acc[i][j], 0, 0, 0);
      }
    }

    if (t + 1 < TILES) STAGE(t + 1);  // overlaps with epilogue below

    float2 cs2[4];
#pragma unroll
    for (int j = 0; j < 4; ++j) cs2[j] = make_float2(0.f, 0.f);

#pragma unroll
    for (int i = 0; i < 2; ++i) {
#pragma unroll
      for (int j = 0; j < 4; ++j) {
        float e0 = __builtin_amdgcn_exp2f(fmaf(acc[i][j][0], m2ca, zbl[i][0] + ebv[j]));
        float e1 = __builtin_amdgcn_exp2f(fmaf(acc[i][j][1], m2ca, zbl[i][1] + ebv[j]));
        float e2 = __builtin_amdgcn_exp2f(fmaf(acc[i][j][2], m2ca, zbl[i][2] + ebv[j]));
        float e3 = __builtin_amdgcn_exp2f(fmaf(acc[i][j][3], m2ca, zbl[i][3] + ebv[j]));
        rs2[i][0].x += e0; rs2[i][0].y += e1;
        rs2[i][1].x += e2; rs2[i][1].y += e3;
        cs2[j].x += e0 + e2; cs2[j].y += e1 + e3;
      }
    }
#pragma unroll
    for (int j = 0; j < 4; ++j) {
      float c = cs2[j].x + cs2[j].y;
      c += __shfl_xor(c, 16);
      c += __shfl_xor(c, 32);
      if (q == 0) atomicAdd(&colacc[t * 64 + j * 16 + l15], c);
    }
  }

  __syncthreads();
  // flush colsum partials (non-atomic: (stripe, split) slice is unique)
  for (int i = tid; i < 1024; i += 256)
    cpart[(size_t)stripe * 8192 + colbase + i] = colacc[i];

  // rowsum: reduce over the 16 lanes (cols) of each quad, flush once
#pragma unroll
  for (int i = 0; i < 2; ++i)
#pragma unroll
    for (int p = 0; p < 2; ++p)
      for (int s = 1; s < 16; s <<= 1) {
        rs2[i][p].x += __shfl_xor(rs2[i][p].x, s);
        rs2[i][p].y += __shfl_xor(rs2[i][p].y, s);
      }
  if (l15 == 0) {
#pragma unroll
    for (int i = 0; i < 2; ++i) {
      int rbase = stripe * 128 + wv * 32 + i * 16 + q * 4;
      rpart[(size_t)split * N_ROWS + rbase + 0] = rs2[i][0].x;
      rpart[(size_t)split * N_ROWS + rbase + 1] = rs2[i][0].y;
      rpart[(size_t)split * N_ROWS + rbase + 2] = rs2[i][1].x;
      rpart[(size_t)split * N_ROWS + rbase + 3] = rs2[i][1].y;
    }
  }
#undef STAGE
}

// ---------------------------------------------------------------------------
// fin: blocks 0..63 rows (sum 8 partials, log); blocks 64..95 cols (sum 128
// partials, log). Block-reduce -> double atomicAdd into dacc[0/1]; last
// block (device-scope ticket) computes both outputs.
// ---------------------------------------------------------------------------
__global__ void fin(const float* __restrict__ rpart, const float* __restrict__ cpart,
                    const float* __restrict__ log_sigma,
                    double* __restrict__ dacc, unsigned* __restrict__ dcnt,
                    float* __restrict__ out) {
  const int tid = threadIdx.x, b = blockIdx.x;
  double v;
  if (b < 64) {
    int row = b * 256 + tid;
    float s = 0.f;
#pragma unroll
    for (int p = 0; p < SPLITS; ++p) s += rpart[(size_t)p * N_ROWS + row];
    v = (double)logf(s);
  } else {
    int col = (b - 64) * 256 + tid;
    float s = 0.f;
#pragma unroll
    for (int p = 0; p < STRIPES; ++p) s += cpart[(size_t)p * M_COLS + col];
    v = (double)logf(s);
  }
  __shared__ double red[256];
  red[tid] = v;
  __syncthreads();
  for (int s = 128; s > 0; s >>= 1) {
    if (tid < s) red[tid] += red[tid + s];
    __syncthreads();
  }
  if (tid == 0) {
    atomicAdd(&dacc[b < 64 ? 0 : 1], red[0]);
    __threadfence();
    unsigned ticket = atomicAdd(dcnt, 1u);
    if (ticket == 95u) {
      double s1 = atomicAdd(&dacc[0], 0.0);  // atomic read-through
      double s2 = atomicAdd(&dacc[1], 0.0);
      float lsv = log_sigma[0];
      float cst = 0.5f * 128.0f * (2.0f * lsv - 1.0f);
      out[0] = (float)(-(s1 / N_ROWS - (double)SHIFT)) + cst + logf((float)M_COLS);
      out[1] = (float)(-(s2 / M_COLS - (double)SHIFT)) + cst + logf((float)N_ROWS);
    }
  }
}

extern "C" void kernel_launch(void* const* d_in, const int* in_sizes, int n_in,
                              void* d_out, int out_size, void* d_ws, size_t ws_size,
                              hipStream_t stream) {
  const float* z  = (const float*)d_in[0];
  const float* e  = (const float*)d_in[1];
  const float* ls = (const float*)d_in[2];
  float* out = (float*)d_out;
  char* ws = (char*)d_ws;
  u16*   zf    = (u16*)ws;                                  // 4 MB
  u16*   ef    = (u16*)(ws + (4u << 20));                   // 2 MB
  float* zsq   = (float*)(ws + (6u << 20));                 // 64 KB
  float* esq   = (float*)(ws + (6u << 20) + (64u << 10));   // 32 KB
  float* rpart = (float*)(ws + (6u << 20) + (96u << 10));   // 8*16384*4 = 512 KB
  float* cpart = (float*)(ws + (6u << 20) + (608u << 10));  // 128*8192*4 = 4 MB
  double* dacc = (double*)(ws + (6u << 20) + (608u << 10) + (4u << 20));
  unsigned* dcnt = (unsigned*)(ws + (6u << 20) + (608u << 10) + (4u << 20) + 16);

  prep<<<dim3(640), dim3(256), 0, stream>>>(z, e, zf, ef, zsq, esq, dacc, dcnt);
  gemm_lse<<<dim3(STRIPES, SPLITS), dim3(256), 0, stream>>>(zf, ef, zsq, esq, ls, rpart, cpart);
  fin<<<dim3(96), dim3(256), 0, stream>>>(rpart, cpart, ls, dacc, dcnt, out);
}

// Round 5
// 138.201 us; speedup vs baseline: 1.1716x; 1.1716x over previous
//
#include <hip/hip_runtime.h>
#include <hip/hip_bf16.h>

typedef unsigned short u16;
typedef __attribute__((ext_vector_type(8))) short short8;
typedef __attribute__((ext_vector_type(4))) float float4v;

#define N_ROWS 16384   // B*H*W = 16*32*32
#define M_COLS 8192
#define KDIM   128
#define SHIFT  64.0f   // fixed lse shift: A<=0, alpha~-0.5 -> exp(A+64) in range
#define STRIPES 64     // 16384 / 256 rows per block
#define SPLITS  16     // col splits; each block covers 512 cols
#define TILES   8      // 512 / 64 cols per tile

// RNE fp32 -> bf16 (data has no NaN)
__device__ inline u16 f2bf(float f) {
  unsigned u = __builtin_bit_cast(unsigned, f);
  unsigned r = (u + 0x7fffu + ((u >> 16) & 1u)) >> 16;
  return (u16)r;
}

// ---------------------------------------------------------------------------
// prep (fused): blocks 0..511 = prep_z (one per (b,h)); blocks 512..639 =
// prep_e. Block 512 also zero-inits the fin ticket/accumulators.
// ---------------------------------------------------------------------------
__global__ void prep(const float* __restrict__ z, const float* __restrict__ e,
                     u16* __restrict__ zf, u16* __restrict__ ef,
                     float* __restrict__ zsq, float* __restrict__ esq,
                     double* __restrict__ dacc, unsigned* __restrict__ dcnt) {
  if (blockIdx.x < 512) {
    const int b = blockIdx.x >> 5, h = blockIdx.x & 31;
    __shared__ float tile[128 * 33];
    __shared__ float psum[8][32];
    const float* src = z + ((size_t)b * 128 * 32 + h) * 32;  // + c*1024 + w
    for (int idx = threadIdx.x; idx < 4096; idx += 256) {
      int c = idx >> 5, w = idx & 31;
      tile[c * 33 + w] = src[c * 1024 + w];
    }
    __syncthreads();
    {
      int w = threadIdx.x & 31, cg = threadIdx.x >> 5;
      float s = 0.f;
#pragma unroll
      for (int cc = 0; cc < 16; ++cc) {
        float v = tile[(cg * 16 + cc) * 33 + w];
        s = fmaf(v, v, s);
      }
      psum[cg][w] = s;
    }
    for (int idx = threadIdx.x; idx < 512; idx += 256) {
      int w = idx >> 4, g = idx & 15;
      short8 v;
#pragma unroll
      for (int cc = 0; cc < 8; ++cc) v[cc] = (short)f2bf(tile[(g * 8 + cc) * 33 + w]);
      *(short8*)&zf[((size_t)b * 1024 + h * 32 + w) * 128 + g * 8] = v;
    }
    __syncthreads();
    if (threadIdx.x < 32) {
      int w = threadIdx.x;
      float s = 0.f;
#pragma unroll
      for (int cg = 0; cg < 8; ++cg) s += psum[cg][w];
      zsq[b * 1024 + h * 32 + w] = s;
    }
  } else {
    if (blockIdx.x == 512 && threadIdx.x == 0) {
      __hip_atomic_store(&dacc[0], 0.0, __ATOMIC_RELAXED, __HIP_MEMORY_SCOPE_AGENT);
      __hip_atomic_store(&dacc[1], 0.0, __ATOMIC_RELAXED, __HIP_MEMORY_SCOPE_AGENT);
      __hip_atomic_store(dcnt, 0u, __ATOMIC_RELAXED, __HIP_MEMORY_SCOPE_AGENT);
    }
    const int gw = ((blockIdx.x - 512) * 256 + threadIdx.x) >> 6;  // 512 waves
    const int ln = threadIdx.x & 63;
    for (int r = gw; r < M_COLS; r += 512) {
      float2 v = *(const float2*)&e[r * 128 + ln * 2];
      unsigned pk = (unsigned)f2bf(v.x) | ((unsigned)f2bf(v.y) << 16);
      *(unsigned*)&ef[r * 128 + ln * 2] = pk;
      float s = fmaf(v.x, v.x, v.y * v.y);
#pragma unroll
      for (int sh = 1; sh < 64; sh <<= 1) s += __shfl_xor(s, sh);
      if (ln == 0) esq[r] = s;
    }
  }
}

// ---------------------------------------------------------------------------
// gemm_lse: persistent-A. Block = 8 waves (512 thr) = 256-row stripe; wave =
// 32 rows, K=128 A-frags in regs (8 x short8 = 32 VGPRs). Loop over 8 B-tiles
// (64 cols) of this block's 512-col split; double-buffered LDS B staging via
// global_load_lds (XOR swizzle), one barrier per tile. Per iter:
// [barrier; mma(t); stage(t+1); epilogue(t)]. rowsum in regs (flushed once);
// colsum: 2 shfl + non-atomic per-wave LDS strip, cross-wave reduce at end.
// Grid 64x16 = 1024 blocks = 2 blocks/CU = 16 waves/CU.
// ---------------------------------------------------------------------------
__global__ __launch_bounds__(512, 4) void gemm_lse(
    const u16* __restrict__ zf, const u16* __restrict__ ef,
    const float* __restrict__ zsq, const float* __restrict__ esq,
    const float* __restrict__ log_sigma,
    float* __restrict__ rpart, float* __restrict__ cpart) {
  __shared__ __align__(16) u16 et[2][64 * 128];  // 2 x 16 KB
  __shared__ float colacc[8][512];               // 16 KB, per-wave private
  const int tid = threadIdx.x;
  const int ln = tid & 63, wv = tid >> 6;        // wv 0..7
  const int l15 = ln & 15, q = ln >> 4;
  const int stripe = blockIdx.x, split = blockIdx.y;
  const int colbase = split * 512;

  // persistent A fragments: 32 rows x K=128 per wave
  short8 af[2][4];
#pragma unroll
  for (int i = 0; i < 2; ++i)
#pragma unroll
    for (int kk = 0; kk < 4; ++kk)
      af[i][kk] = *(const short8*)(zf +
          (size_t)(stripe * 256 + wv * 32 + i * 16 + l15) * 128 + kk * 32 + q * 8);

  const float lsv = log_sigma[0];
  const float sg = __expf(lsv);
  const float alpha = -0.5f / (sg * sg);
  const float L2E = 1.44269504088896f;
  const float ca = alpha * L2E, cb = SHIFT * L2E, m2ca = -2.0f * ca;

  float4v zbl[2];
#pragma unroll
  for (int i = 0; i < 2; ++i) {
    float4v zs = *(const float4v*)(zsq + stripe * 256 + wv * 32 + i * 16 + q * 4);
#pragma unroll
    for (int r = 0; r < 4; ++r) zbl[i][r] = fmaf(ca, zs[r], cb);
  }

  float2 rs2[2][2];
#pragma unroll
  for (int i = 0; i < 2; ++i)
#pragma unroll
    for (int p = 0; p < 2; ++p) rs2[i][p] = make_float2(0.f, 0.f);

  // staging: 1024 16B-units per tile, 512 threads -> 2 each
#define STAGE(tt)                                                              \
  do {                                                                         \
    const u16* efb = ef + (size_t)(colbase + (tt) * 64) * 128;                 \
    u16* dstb = et[(tt) & 1];                                                  \
    _Pragma("unroll")                                                          \
    for (int it = 0; it < 2; ++it) {                                           \
      int u = it * 512 + tid;                                                  \
      int r = u >> 4, p_ = u & 15;                                             \
      int g = p_ ^ (r & 15);                                                   \
      __builtin_amdgcn_global_load_lds(                                        \
          (const __attribute__((address_space(1))) unsigned int*)(efb + r * 128 + g * 8), \
          (__attribute__((address_space(3))) unsigned int*)(dstb + (it * 512 + wv * 64) * 8), \
          16, 0, 0);                                                           \
    }                                                                          \
  } while (0)

  STAGE(0);

  for (int t = 0; t < TILES; ++t) {
    // hoist esq loads so the epilogue doesn't stall on them
    float ebv[4];
#pragma unroll
    for (int j = 0; j < 4; ++j) ebv[j] = ca * esq[colbase + t * 64 + j * 16 + l15];

    __syncthreads();
    const u16* bb = et[t & 1];

    float4v acc[2][4];
#pragma unroll
    for (int kk = 0; kk < 4; ++kk) {
      short8 bfr[4];
      const int poff = ((kk * 4 + q) ^ l15) * 8;
#pragma unroll
      for (int j = 0; j < 4; ++j)
        bfr[j] = *(const short8*)(bb + (j * 16 + l15) * 128 + poff);
      if (kk == 0) {
#pragma unroll
        for (int i = 0; i < 2; ++i)
#pragma unroll
          for (int j = 0; j < 4; ++j)
            acc[i][j] = __builtin_amdgcn_mfma_f32_16x16x32_bf16(
                af[i][0], bfr[j], (float4v){0.f, 0.f, 0.f, 0.f}, 0, 0, 0);
      } else {
#pragma unroll
        for (int i = 0; i < 2; ++i)
#pragma unroll
          for (int j = 0; j < 4; ++j)
            acc[i][j] = __builtin_amdgcn_mfma_f32_16x16x32_bf16(
                af[i][kk], bfr[j], acc[i][j], 0, 0, 0);
      }
    }

    if (t + 1 < TILES) STAGE(t + 1);  // overlaps with epilogue below

    float2 cs2[4];
#pragma unroll
    for (int j = 0; j < 4; ++j) cs2[j] = make_float2(0.f, 0.f);

#pragma unroll
    for (int i = 0; i < 2; ++i) {
#pragma unroll
      for (int j = 0; j < 4; ++j) {
        float e0 = __builtin_amdgcn_exp2f(fmaf(acc[i][j][0], m2ca, zbl[i][0] + ebv[j]));
        float e1 = __builtin_amdgcn_exp2f(fmaf(acc[i][j][1], m2ca, zbl[i][1] + ebv[j]));
        float e2 = __builtin_amdgcn_exp2f(fmaf(acc[i][j][2], m2ca, zbl[i][2] + ebv[j]));
        float e3 = __builtin_amdgcn_exp2f(fmaf(acc[i][j][3], m2ca, zbl[i][3] + ebv[j]));
        rs2[i][0].x += e0; rs2[i][0].y += e1;
        rs2[i][1].x += e2; rs2[i][1].y += e3;
        cs2[j].x += e0 + e2; cs2[j].y += e1 + e3;
      }
    }
    // colsum: fold quads (bits 4,5), then q==0 writes per-wave strip
#pragma unroll
    for (int j = 0; j < 4; ++j) {
      float c = cs2[j].x + cs2[j].y;
      c += __shfl_xor(c, 16);
      c += __shfl_xor(c, 32);
      if (q == 0) colacc[wv][t * 64 + j * 16 + l15] = c;
    }
  }

  __syncthreads();
  // cross-wave colsum reduce: 512 threads, one col each
  {
    float s = 0.f;
#pragma unroll
    for (int w = 0; w < 8; ++w) s += colacc[w][tid];
    cpart[(size_t)stripe * M_COLS + colbase + tid] = s;
  }

  // rowsum: reduce over the 16 lanes (cols) of each quad, flush once
#pragma unroll
  for (int i = 0; i < 2; ++i)
#pragma unroll
    for (int p = 0; p < 2; ++p)
      for (int s = 1; s < 16; s <<= 1) {
        rs2[i][p].x += __shfl_xor(rs2[i][p].x, s);
        rs2[i][p].y += __shfl_xor(rs2[i][p].y, s);
      }
  if (l15 == 0) {
#pragma unroll
    for (int i = 0; i < 2; ++i) {
      int rbase = stripe * 256 + wv * 32 + i * 16 + q * 4;
      rpart[(size_t)split * N_ROWS + rbase + 0] = rs2[i][0].x;
      rpart[(size_t)split * N_ROWS + rbase + 1] = rs2[i][0].y;
      rpart[(size_t)split * N_ROWS + rbase + 2] = rs2[i][1].x;
      rpart[(size_t)split * N_ROWS + rbase + 3] = rs2[i][1].y;
    }
  }
#undef STAGE
}

// ---------------------------------------------------------------------------
// fin: blocks 0..63 rows (sum 16 partials, log); blocks 64..95 cols (sum 64
// partials, log). Block-reduce -> double atomicAdd into dacc[0/1]; last
// block (device-scope ticket) computes both outputs.
// ---------------------------------------------------------------------------
__global__ void fin(const float* __restrict__ rpart, const float* __restrict__ cpart,
                    const float* __restrict__ log_sigma,
                    double* __restrict__ dacc, unsigned* __restrict__ dcnt,
                    float* __restrict__ out) {
  const int tid = threadIdx.x, b = blockIdx.x;
  double v;
  if (b < 64) {
    int row = b * 256 + tid;
    float s = 0.f;
#pragma unroll
    for (int p = 0; p < SPLITS; ++p) s += rpart[(size_t)p * N_ROWS + row];
    v = (double)logf(s);
  } else {
    int col = (b - 64) * 256 + tid;
    float s = 0.f;
#pragma unroll
    for (int p = 0; p < STRIPES; ++p) s += cpart[(size_t)p * M_COLS + col];
    v = (double)logf(s);
  }
  __shared__ double red[256];
  red[tid] = v;
  __syncthreads();
  for (int s = 128; s > 0; s >>= 1) {
    if (tid < s) red[tid] += red[tid + s];
    __syncthreads();
  }
  if (tid == 0) {
    atomicAdd(&dacc[b < 64 ? 0 : 1], red[0]);
    __threadfence();
    unsigned ticket = atomicAdd(dcnt, 1u);
    if (ticket == 95u) {
      double s1 = atomicAdd(&dacc[0], 0.0);  // atomic read-through
      double s2 = atomicAdd(&dacc[1], 0.0);
      float lsv = log_sigma[0];
      float cst = 0.5f * 128.0f * (2.0f * lsv - 1.0f);
      out[0] = (float)(-(s1 / N_ROWS - (double)SHIFT)) + cst + logf((float)M_COLS);
      out[1] = (float)(-(s2 / M_COLS - (double)SHIFT)) + cst + logf((float)N_ROWS);
    }
  }
}

extern "C" void kernel_launch(void* const* d_in, const int* in_sizes, int n_in,
                              void* d_out, int out_size, void* d_ws, size_t ws_size,
                              hipStream_t stream) {
  const float* z  = (const float*)d_in[0];
  const float* e  = (const float*)d_in[1];
  const float* ls = (const float*)d_in[2];
  float* out = (float*)d_out;
  char* ws = (char*)d_ws;
  u16*   zf    = (u16*)ws;                                  // 4 MB
  u16*   ef    = (u16*)(ws + (4u << 20));                   // 2 MB
  float* zsq   = (float*)(ws + (6u << 20));                 // 64 KB
  float* esq   = (float*)(ws + (6u << 20) + (64u << 10));   // 32 KB
  float* rpart = (float*)(ws + (6u << 20) + (96u << 10));   // 16*16384*4 = 1 MB
  float* cpart = (float*)(ws + (7u << 20) + (96u << 10));   // 64*8192*4 = 2 MB
  double* dacc = (double*)(ws + (9u << 20) + (96u << 10));
  unsigned* dcnt = (unsigned*)(ws + (9u << 20) + (96u << 10) + 16);

  prep<<<dim3(640), dim3(256), 0, stream>>>(z, e, zf, ef, zsq, esq, dacc, dcnt);
  gemm_lse<<<dim3(STRIPES, SPLITS), dim3(512), 0, stream>>>(zf, ef, zsq, esq, ls, rpart, cpart);
  fin<<<dim3(96), dim3(256), 0, stream>>>(rpart, cpart, ls, dacc, dcnt, out);
}